// Round 1
// baseline (200.326 us; speedup 1.0000x reference)
//
#include <hip/hip_runtime.h>
#include <math.h>

#define C_CLS   19
#define H_IN    97
#define W_IN    97
#define H_OUT   769
#define W_OUT   769
#define N_BATCH 4
#define NPIX    (N_BATCH * H_OUT * W_OUT)   // 2,365,444
#define IGNORE_LBL 255
#define MIN_KEPT   100000
#define OHEM_THRESH 0.7f
#define NHI     110    // histogram bins for p in (0.7, 1.0]
#define ACC_STRIDE 1024  // floats per pred accumulator block in ws

// Cityscapes class weights
__device__ const float c_class_w[C_CLS] = {
    0.8373f, 0.918f,  0.866f,  1.0345f, 1.0166f, 0.9969f, 0.9754f,
    1.0489f, 0.8786f, 1.0023f, 0.9539f, 0.9843f, 1.1116f, 0.9037f,
    1.0865f, 1.0955f, 1.0865f, 1.1529f, 1.0507f};

// ws float layout per pred (pr*ACC_STRIDE):
// [0] sum_w (p<=0.7,valid)  [1] sum_w*nll  [2] count(p<=0.7)  [3] count(valid)
// [4..113] hi_cnt  [114..223] hi_sum_w  [224..333] hi_sum_wnll

__global__ __launch_bounds__(256) void ohem_pass1(
    const float* __restrict__ pred1, const float* __restrict__ pred2,
    const int* __restrict__ target, float* __restrict__ ws)
{
    const int pr = blockIdx.y;
    const float* __restrict__ pred = pr ? pred2 : pred1;
    float* __restrict__ acc = ws + pr * ACC_STRIDE;

    __shared__ float sh_hi_cnt[NHI];
    __shared__ float sh_hi_sw[NHI];
    __shared__ float sh_hi_swlp[NHI];
    __shared__ float sh_red[4][4];

    for (int i = threadIdx.x; i < NHI; i += 256) {
        sh_hi_cnt[i] = 0.0f; sh_hi_sw[i] = 0.0f; sh_hi_swlp[i] = 0.0f;
    }
    __syncthreads();

    float a_w = 0.0f, a_wlp = 0.0f, a_cle = 0.0f, a_nv = 0.0f;
    const float scl = (float)H_IN / (float)H_OUT;  // 97/769, same for x & y

    for (int idx = blockIdx.x * 256 + threadIdx.x; idx < NPIX;
         idx += gridDim.x * 256) {
        // decompose idx -> n, y, x
        int n   = idx / (H_OUT * W_OUT);
        int rem = idx - n * (H_OUT * W_OUT);
        int y   = rem / W_OUT;
        int x   = rem - y * W_OUT;

        int t = target[idx];
        bool valid = (t != IGNORE_LBL);
        int ts = valid ? t : 0;
        if (ts < 0) ts = 0;
        if (ts >= C_CLS) ts = C_CLS - 1;

        // half-pixel-center source coords, clamped (matches jax.image.resize
        // 'bilinear' == torch upsample align_corners=False)
        float sy = fmaxf(fmaf((float)y + 0.5f, scl, -0.5f), 0.0f);
        float sx = fmaxf(fmaf((float)x + 0.5f, scl, -0.5f), 0.0f);
        int y0 = (int)sy; y0 = min(y0, H_IN - 1);
        int x0 = (int)sx; x0 = min(x0, W_IN - 1);
        float fy = sy - (float)y0;
        float fx = sx - (float)x0;
        int y1 = min(y0 + 1, H_IN - 1);
        int x1 = min(x0 + 1, W_IN - 1);

        float w00 = (1.0f - fy) * (1.0f - fx);
        float w01 = (1.0f - fy) * fx;
        float w10 = fy * (1.0f - fx);
        float w11 = fy * fx;

        const float* base = pred + (size_t)n * (C_CLS * H_IN * W_IN);
        int o00 = y0 * W_IN + x0;
        int o01 = y0 * W_IN + x1;
        int o10 = y1 * W_IN + x0;
        int o11 = y1 * W_IN + x1;

        // online softmax over channels; capture logit of true class
        float m = -1e30f, s = 0.0f, lt = 0.0f;
        #pragma unroll
        for (int c = 0; c < C_CLS; ++c) {
            int co = c * (H_IN * W_IN);
            float v = w00 * base[co + o00] + w01 * base[co + o01]
                    + w10 * base[co + o10] + w11 * base[co + o11];
            float nm = fmaxf(m, v);
            s = s * __expf(m - nm) + __expf(v - nm);
            m = nm;
            if (c == ts) lt = v;
        }

        if (valid) {
            a_nv += 1.0f;
            float d   = lt - m;
            float p   = __expf(d) / s;       // true-class prob
            float nll = __logf(s) - d;       // -log p
            float w   = c_class_w[ts];
            if (p <= OHEM_THRESH) {
                a_w   += w;
                a_wlp += w * nll;
                a_cle += 1.0f;
            } else {
                int b = (int)((p - OHEM_THRESH) * (109.0f / 0.3f));
                b = min(max(b, 0), NHI - 1);
                atomicAdd(&sh_hi_cnt[b], 1.0f);
                atomicAdd(&sh_hi_sw[b], w);
                atomicAdd(&sh_hi_swlp[b], w * nll);
            }
        }
    }

    // wave-level butterfly reduce (wave = 64)
    #pragma unroll
    for (int off = 32; off > 0; off >>= 1) {
        a_w   += __shfl_down(a_w, off);
        a_wlp += __shfl_down(a_wlp, off);
        a_cle += __shfl_down(a_cle, off);
        a_nv  += __shfl_down(a_nv, off);
    }
    int lane = threadIdx.x & 63;
    int wv   = threadIdx.x >> 6;
    if (lane == 0) {
        sh_red[wv][0] = a_w; sh_red[wv][1] = a_wlp;
        sh_red[wv][2] = a_cle; sh_red[wv][3] = a_nv;
    }
    __syncthreads();
    if (threadIdx.x == 0) {
        float w = 0, wl = 0, cl = 0, nv = 0;
        #pragma unroll
        for (int i = 0; i < 4; ++i) {
            w += sh_red[i][0]; wl += sh_red[i][1];
            cl += sh_red[i][2]; nv += sh_red[i][3];
        }
        atomicAdd(&acc[0], w);
        atomicAdd(&acc[1], wl);
        atomicAdd(&acc[2], cl);
        atomicAdd(&acc[3], nv);
    }
    // flush rare high-p histogram (writes all completed before barrier above)
    for (int i = threadIdx.x; i < NHI; i += 256) {
        if (sh_hi_cnt[i] != 0.0f) {
            atomicAdd(&acc[4 + i], sh_hi_cnt[i]);
            atomicAdd(&acc[114 + i], sh_hi_sw[i]);
            atomicAdd(&acc[224 + i], sh_hi_swlp[i]);
        }
    }
}

__global__ void ohem_finalize(const float* __restrict__ ws, float* __restrict__ out)
{
    if (threadIdx.x != 0 || blockIdx.x != 0) return;
    float loss[2];
    for (int pr = 0; pr < 2; ++pr) {
        const float* a = ws + pr * ACC_STRIDE;
        float sw = a[0], swlp = a[1], cle = a[2], nv = a[3];
        float l;
        if (nv <= (float)MIN_KEPT) {
            // min_kept >= num_valid: keep all valid pixels
            float tw = sw, twlp = swlp;
            for (int b = 0; b < NHI; ++b) { tw += a[114 + b]; twlp += a[224 + b]; }
            l = twlp / tw;
        } else if (cle >= (float)MIN_KEPT) {
            // k-th smallest p <= 0.7  =>  threshold = 0.7: keep exactly p<=0.7
            l = swlp / sw;
        } else {
            // th_pred > 0.7: walk high-p histogram until rank min_kept reached
            float cum = cle, tw = sw, twlp = swlp;
            for (int b = 0; b < NHI; ++b) {
                cum  += a[4 + b];
                tw   += a[114 + b];
                twlp += a[224 + b];
                if (cum >= (float)MIN_KEPT) break;
            }
            l = twlp / tw;
        }
        loss[pr] = l;
    }
    out[0] = 0.4f * loss[0] + loss[1];
}

extern "C" void kernel_launch(void* const* d_in, const int* in_sizes, int n_in,
                              void* d_out, int out_size, void* d_ws, size_t ws_size,
                              hipStream_t stream)
{
    const float* pred1  = (const float*)d_in[0];
    const float* pred2  = (const float*)d_in[1];
    const int*   target = (const int*)d_in[2];
    float* out = (float*)d_out;
    float* ws  = (float*)d_ws;

    hipMemsetAsync(d_ws, 0, 2 * ACC_STRIDE * sizeof(float), stream);

    dim3 grid(2048, 2);
    ohem_pass1<<<grid, 256, 0, stream>>>(pred1, pred2, target, ws);
    ohem_finalize<<<1, 64, 0, stream>>>(ws, out);
}

// Round 2
// 139.138 us; speedup vs baseline: 1.4398x; 1.4398x over previous
//
#include <hip/hip_runtime.h>
#include <math.h>

#define C_CLS   19
#define H_IN    97
#define W_IN    97
#define HW_IN   (H_IN * W_IN)
#define CHW_IN  (C_CLS * HW_IN)
#define H_OUT   769
#define W_OUT   769
#define N_BATCH 4
#define NPIX    (N_BATCH * H_OUT * W_OUT)   // 2,365,444
#define IGNORE_LBL 255
#define MIN_KEPT   100000
#define NHI     110          // histogram bins for p in (0.7, 1.0]
#define ACC_STRIDE 1024      // floats per pred accumulator block in ws
#define NLL_THR 0.35667494f  // -ln(0.7); p <= 0.7  <=>  nll >= NLL_THR

// Cityscapes class weights
__device__ const float c_class_w[C_CLS] = {
    0.8373f, 0.918f,  0.866f,  1.0345f, 1.0166f, 0.9969f, 0.9754f,
    1.0489f, 0.8786f, 1.0023f, 0.9539f, 0.9843f, 1.1116f, 0.9037f,
    1.0865f, 1.0955f, 1.0865f, 1.1529f, 1.0507f};

// ws float layout per pred (pr*ACC_STRIDE):
// [0] sum_w (p<=0.7,valid)  [1] sum_w*nll  [2] count(p<=0.7)  [3] count(valid)
// [4..113] hi_cnt  [114..223] hi_sum_w  [224..333] hi_sum_wnll

__device__ __forceinline__ float max19(const float v[C_CLS]) {
    // depth-5 tree; fmax chains are short and independent
    float p0 = fmaxf(v[0], v[1]);
    float p1 = fmaxf(v[2], v[3]);
    float p2 = fmaxf(v[4], v[5]);
    float p3 = fmaxf(v[6], v[7]);
    float p4 = fmaxf(v[8], v[9]);
    float p5 = fmaxf(v[10], v[11]);
    float p6 = fmaxf(v[12], v[13]);
    float p7 = fmaxf(v[14], v[15]);
    float p8 = fmaxf(v[16], v[17]);
    p0 = fmaxf(p0, p1); p2 = fmaxf(p2, p3);
    p4 = fmaxf(p4, p5); p6 = fmaxf(p6, p7);
    p8 = fmaxf(p8, v[18]);
    p0 = fmaxf(p0, p2); p4 = fmaxf(p4, p6);
    return fmaxf(fmaxf(p0, p4), p8);
}

__device__ __forceinline__ float expsum19(const float v[C_CLS], float m) {
    // 4 independent partial sums; 19 independent expf
    float s0 = 0.0f, s1 = 0.0f, s2 = 0.0f, s3 = 0.0f;
    #pragma unroll
    for (int c = 0; c < 16; c += 4) {
        s0 += __expf(v[c + 0] - m);
        s1 += __expf(v[c + 1] - m);
        s2 += __expf(v[c + 2] - m);
        s3 += __expf(v[c + 3] - m);
    }
    s0 += __expf(v[16] - m);
    s1 += __expf(v[17] - m);
    s2 += __expf(v[18] - m);
    return (s0 + s1) + (s2 + s3);
}

__global__ __launch_bounds__(256) void ohem_pass1(
    const float* __restrict__ pred1, const float* __restrict__ pred2,
    const int* __restrict__ target, float* __restrict__ ws)
{
    __shared__ float sh_hi[2][3][NHI];   // [pred][cnt/sw/swlp][bin]
    __shared__ float sh_red[4][8];

    for (int i = threadIdx.x; i < 2 * 3 * NHI; i += 256)
        (&sh_hi[0][0][0])[i] = 0.0f;
    __syncthreads();

    float a_nv = 0.0f;
    float a_w1 = 0.0f, a_wlp1 = 0.0f, a_cle1 = 0.0f;
    float a_w2 = 0.0f, a_wlp2 = 0.0f, a_cle2 = 0.0f;
    const float scl = (float)H_IN / (float)H_OUT;

    for (int idx = blockIdx.x * 256 + threadIdx.x; idx < NPIX;
         idx += gridDim.x * 256) {
        int n   = idx / (H_OUT * W_OUT);
        int rem = idx - n * (H_OUT * W_OUT);
        int y   = rem / W_OUT;
        int x   = rem - y * W_OUT;

        int t = target[idx];
        bool valid = (t != IGNORE_LBL);
        int ts = valid ? t : 0;

        float sy = fmaxf(fmaf((float)y + 0.5f, scl, -0.5f), 0.0f);
        float sx = fmaxf(fmaf((float)x + 0.5f, scl, -0.5f), 0.0f);
        int y0 = min((int)sy, H_IN - 1);
        int x0 = min((int)sx, W_IN - 1);
        float fy = sy - (float)y0;
        float fx = sx - (float)x0;
        int y1 = min(y0 + 1, H_IN - 1);
        int x1 = min(x0 + 1, W_IN - 1);

        float w00 = (1.0f - fy) * (1.0f - fx);
        float w01 = (1.0f - fy) * fx;
        float w10 = fy * (1.0f - fx);
        float w11 = fy * fx;

        const float* b1 = pred1 + (size_t)n * CHW_IN;
        const float* b2 = pred2 + (size_t)n * CHW_IN;
        int o00 = y0 * W_IN + x0;
        int o01 = y0 * W_IN + x1;
        int o10 = y1 * W_IN + x0;
        int o11 = y1 * W_IN + x1;

        // phase 1: all interpolated logits into registers (loads pipeline)
        float v1[C_CLS], v2[C_CLS];
        #pragma unroll
        for (int c = 0; c < C_CLS; ++c) {
            int co = c * HW_IN;
            v1[c] = w00 * b1[co + o00] + w01 * b1[co + o01]
                  + w10 * b1[co + o10] + w11 * b1[co + o11];
            v2[c] = w00 * b2[co + o00] + w01 * b2[co + o01]
                  + w10 * b2[co + o10] + w11 * b2[co + o11];
        }
        // true-class logit via static-unrolled select (no scratch)
        float lt1 = v1[0], lt2 = v2[0];
        #pragma unroll
        for (int c = 1; c < C_CLS; ++c) {
            lt1 = (ts == c) ? v1[c] : lt1;
            lt2 = (ts == c) ? v2[c] : lt2;
        }

        // phase 2: two independent softmax reductions
        float m1 = max19(v1);
        float m2 = max19(v2);
        float s1 = expsum19(v1, m1);
        float s2 = expsum19(v2, m2);

        if (valid) {
            a_nv += 1.0f;
            float w = c_class_w[ts];
            float nll1 = __logf(s1) - (lt1 - m1);
            float nll2 = __logf(s2) - (lt2 - m2);

            if (nll1 >= NLL_THR) {            // p1 <= 0.7
                a_w1 += w; a_wlp1 += w * nll1; a_cle1 += 1.0f;
            } else {
                float p = __expf(-nll1);
                int b = min(max((int)((p - 0.7f) * (109.0f / 0.3f)), 0), NHI - 1);
                atomicAdd(&sh_hi[0][0][b], 1.0f);
                atomicAdd(&sh_hi[0][1][b], w);
                atomicAdd(&sh_hi[0][2][b], w * nll1);
            }
            if (nll2 >= NLL_THR) {            // p2 <= 0.7
                a_w2 += w; a_wlp2 += w * nll2; a_cle2 += 1.0f;
            } else {
                float p = __expf(-nll2);
                int b = min(max((int)((p - 0.7f) * (109.0f / 0.3f)), 0), NHI - 1);
                atomicAdd(&sh_hi[1][0][b], 1.0f);
                atomicAdd(&sh_hi[1][1][b], w);
                atomicAdd(&sh_hi[1][2][b], w * nll2);
            }
        }
    }

    // wave butterfly reduce, 7 values
    #pragma unroll
    for (int off = 32; off > 0; off >>= 1) {
        a_nv   += __shfl_down(a_nv, off);
        a_w1   += __shfl_down(a_w1, off);
        a_wlp1 += __shfl_down(a_wlp1, off);
        a_cle1 += __shfl_down(a_cle1, off);
        a_w2   += __shfl_down(a_w2, off);
        a_wlp2 += __shfl_down(a_wlp2, off);
        a_cle2 += __shfl_down(a_cle2, off);
    }
    int lane = threadIdx.x & 63;
    int wv   = threadIdx.x >> 6;
    if (lane == 0) {
        sh_red[wv][0] = a_nv;
        sh_red[wv][1] = a_w1; sh_red[wv][2] = a_wlp1; sh_red[wv][3] = a_cle1;
        sh_red[wv][4] = a_w2; sh_red[wv][5] = a_wlp2; sh_red[wv][6] = a_cle2;
    }
    __syncthreads();
    if (threadIdx.x == 0) {
        float r[7] = {0, 0, 0, 0, 0, 0, 0};
        #pragma unroll
        for (int i = 0; i < 4; ++i)
            #pragma unroll
            for (int j = 0; j < 7; ++j) r[j] += sh_red[i][j];
        atomicAdd(&ws[0], r[1]); atomicAdd(&ws[1], r[2]);
        atomicAdd(&ws[2], r[3]); atomicAdd(&ws[3], r[0]);
        atomicAdd(&ws[ACC_STRIDE + 0], r[4]); atomicAdd(&ws[ACC_STRIDE + 1], r[5]);
        atomicAdd(&ws[ACC_STRIDE + 2], r[6]); atomicAdd(&ws[ACC_STRIDE + 3], r[0]);
    }
    for (int i = threadIdx.x; i < NHI; i += 256) {
        if (sh_hi[0][0][i] != 0.0f) {
            atomicAdd(&ws[4 + i],   sh_hi[0][0][i]);
            atomicAdd(&ws[114 + i], sh_hi[0][1][i]);
            atomicAdd(&ws[224 + i], sh_hi[0][2][i]);
        }
        if (sh_hi[1][0][i] != 0.0f) {
            atomicAdd(&ws[ACC_STRIDE + 4 + i],   sh_hi[1][0][i]);
            atomicAdd(&ws[ACC_STRIDE + 114 + i], sh_hi[1][1][i]);
            atomicAdd(&ws[ACC_STRIDE + 224 + i], sh_hi[1][2][i]);
        }
    }
}

__global__ void ohem_finalize(const float* __restrict__ ws, float* __restrict__ out)
{
    if (threadIdx.x != 0 || blockIdx.x != 0) return;
    float loss[2];
    for (int pr = 0; pr < 2; ++pr) {
        const float* a = ws + pr * ACC_STRIDE;
        float sw = a[0], swlp = a[1], cle = a[2], nv = a[3];
        float l;
        if (nv <= (float)MIN_KEPT) {
            float tw = sw, twlp = swlp;
            for (int b = 0; b < NHI; ++b) { tw += a[114 + b]; twlp += a[224 + b]; }
            l = twlp / tw;
        } else if (cle >= (float)MIN_KEPT) {
            l = swlp / sw;
        } else {
            float cum = cle, tw = sw, twlp = swlp;
            for (int b = 0; b < NHI; ++b) {
                cum  += a[4 + b];
                tw   += a[114 + b];
                twlp += a[224 + b];
                if (cum >= (float)MIN_KEPT) break;
            }
            l = twlp / tw;
        }
        loss[pr] = l;
    }
    out[0] = 0.4f * loss[0] + loss[1];
}

extern "C" void kernel_launch(void* const* d_in, const int* in_sizes, int n_in,
                              void* d_out, int out_size, void* d_ws, size_t ws_size,
                              hipStream_t stream)
{
    const float* pred1  = (const float*)d_in[0];
    const float* pred2  = (const float*)d_in[1];
    const int*   target = (const int*)d_in[2];
    float* out = (float*)d_out;
    float* ws  = (float*)d_ws;

    hipMemsetAsync(d_ws, 0, 2 * ACC_STRIDE * sizeof(float), stream);

    ohem_pass1<<<dim3(2048), 256, 0, stream>>>(pred1, pred2, target, ws);
    ohem_finalize<<<1, 64, 0, stream>>>(ws, out);
}